// Round 1
// baseline (507.240 us; speedup 1.0000x reference)
//
#include <hip/hip_runtime.h>
#include <hip/hip_fp16.h>

#define NN 8192
#define MM 8192
#define FD 128
#define EDm 128
#define HD 64
#define NH 4
#define NTILE 32

typedef float f32x4 __attribute__((ext_vector_type(4)));
typedef _Float16 h16x8 __attribute__((ext_vector_type(8)));
typedef unsigned int u32;

// Fused: per-block recompute of vf[h][f] = Wf[h][f][:].a[h][:], then
// esrc[h][n] = F0[n,:] . vf[h,:]   (grid = 128 blocks -> full n coverage)
__global__ void k_esrc(const float* __restrict__ F0, const float* __restrict__ Wf,
                       const float* __restrict__ a, float* __restrict__ esrc) {
  __shared__ float vfL[NH * FD];
  int t = threadIdx.x;  // 256
#pragma unroll
  for (int r = 0; r < 2; ++r) {
    int idx = t + r * 256;            // 512 entries
    int h = idx >> 7, f = idx & 127;
    const float* w = Wf + (size_t)(h * FD + f) * HD;
    const float* av = a + h * HD;
    float s = 0.f;
#pragma unroll
    for (int d = 0; d < HD; ++d) s += w[d] * av[d];
    vfL[idx] = s;
  }
  __syncthreads();
  int g = blockIdx.x * 256 + t;       // 0..32767
  int n = g >> 2, h = g & 3;
  const float4* fr = (const float4*)(F0 + (size_t)n * FD);
  const float4* vr = (const float4*)(vfL + h * FD);
  float s = 0.f;
#pragma unroll
  for (int i = 0; i < FD / 4; ++i) {
    float4 x = fr[i], y = vr[i];
    s += x.x * y.x + x.y * y.y + x.z * y.z + x.w * y.w;
  }
  esrc[h * NN + n] = s;
}

// E1 = E0·We per head; writes Bp directly in MFMA-B fragment order
// (wave = 8 m-rows, lane = d), plus ed/ed2 fp16 exp tables. No E1T pass.
__global__ void k_e1(const float* __restrict__ E0, const float* __restrict__ We,
                     const float* __restrict__ a, uint4* __restrict__ Bp,
                     _Float16* __restrict__ edh, _Float16* __restrict__ ed2h) {
  int wid = (blockIdx.x * blockDim.x + threadIdx.x) >> 6;  // 4096 waves
  int lane = threadIdx.x & 63;
  int h = wid >> 10;
  int mg = wid & 1023;
  int m = mg * 8;
  const float* we = We + (size_t)h * EDm * HD + lane;
  const float* e0r = E0 + (size_t)m * EDm;
  float ac[8] = {};
#pragma unroll 4
  for (int e = 0; e < EDm; ++e) {
    float wv = we[e * HD];
#pragma unroll
    for (int j = 0; j < 8; ++j) ac[j] += e0r[j * EDm + e] * wv;
  }
  // Bp[h][mc][dt][quad*16+col]: 8 fp16 (m..m+7) at d = dt*16+col
  int mc = mg >> 2, quad = mg & 3, dt = lane >> 4, col = lane & 15;
  union { h16x8 v; uint4 u; } hv;
#pragma unroll
  for (int j = 0; j < 8; ++j) hv.v[j] = (_Float16)ac[j];
  Bp[(((size_t)h * 256 + mc) * 4 + dt) * 64 + quad * 16 + col] = hv.u;

  float av = a[h * HD + lane];
  float d[8];
#pragma unroll
  for (int j = 0; j < 8; ++j) d[j] = ac[j] * av;
#pragma unroll
  for (int o = 32; o; o >>= 1)
#pragma unroll
    for (int j = 0; j < 8; ++j) d[j] += __shfl_xor(d[j], o);
  if (lane == 0) {
    const float L2E = 1.4426950408889634f;
    union { h16x8 v; uint4 u; } e1, e2;
#pragma unroll
    for (int j = 0; j < 8; ++j) {
      e1.v[j] = (_Float16)exp2f(d[j] * L2E);
      e2.v[j] = (_Float16)exp2f(0.2f * d[j] * L2E);
    }
    *(uint4*)(edh + (size_t)h * MM + m) = e1.u;
    *(uint4*)(ed2h + (size_t)h * MM + m) = e2.u;
  }
}

// bit b0 at `bit`, b1 at bit+1 -> (b0?0xffff:0)|(b1?0xffff0000:0)
__device__ __forceinline__ u32 hm2b(u32 w, int bit) {
  return (((w >> bit) & 1u) | (((w >> (bit + 1)) & 1u) << 16)) * 0xffffu;
}

// Main: 256 blocks x 1024 thr. m is chunked 4 x 2048 with double-buffered
// ballot bit-words in LDS: while chunk c is consumed (MFMA), each wave also
// streams + ballots its 2 A-rows for chunk c+1. One barrier per chunk; only
// chunk 0's ballot (64 MB of A) is exposed. A read once chip-wide (nt loads).
__global__ __launch_bounds__(1024, 4) void k_main(
    const int* __restrict__ A, const uint4* __restrict__ Bp,
    const float* __restrict__ esrc, const _Float16* __restrict__ edh,
    const _Float16* __restrict__ ed2h, float* __restrict__ out) {
  __shared__ __align__(16) char smem[41472];
  u32* bits = (u32*)smem;              // [2][32 rows][65 words] dbuf = 16640 B
  float* Hsum = (float*)smem;          // epilogue alias: [4][32][64] 32 KB
  float* Dsum = (float*)(smem + 32768);// [4][32]
  float* hp = (float*)(smem + 33280);  // [32][64]

  const int t = threadIdx.x;
  const int lane = t & 63;
  const int wv = t >> 6;       // 0..15
  const int h = wv & 3;        // head
  const int q = wv >> 2;       // m sub-quarter within chunk (512 m)
  const int col = lane & 15;
  const int quad = lane >> 4;
  const int qs = quad * 8;
  const int n0 = blockIdx.x * NTILE;
  const float L2E = 1.4426950408889634f;

  // producer row pointers (wave wv owns rows 2wv, 2wv+1)
  const int r0 = wv * 2, r1 = r0 + 1;
  const int* aP0 = A + (size_t)(n0 + r0) * MM + lane;
  const int* aP1 = A + (size_t)(n0 + r1) * MM + lane;

  const _Float16* edp = edh + (size_t)h * MM + qs;
  const _Float16* e2p = ed2h + (size_t)h * MM + qs;
  const uint4* bp = Bp + (size_t)h * 65536 + lane;

  // global B pipeline: preload iter (c=0, it=0); completes during prologue
  int mc = q * 16;
  uint4 bu0 = bp[(size_t)mc * 256];
  uint4 bu1 = bp[(size_t)mc * 256 + 64];
  uint4 bu2 = bp[(size_t)mc * 256 + 128];
  uint4 bu3 = bp[(size_t)mc * 256 + 192];

  float s0 = esrc[h * NN + n0 + col];
  float s1 = esrc[h * NN + n0 + 16 + col];
  _Float16 e80 = (_Float16)exp2f(0.8f * s0 * L2E);
  _Float16 e81 = (_Float16)exp2f(0.8f * s1 * L2E);
  h16x8 es80 = {e80, e80, e80, e80, e80, e80, e80, e80};
  h16x8 es81 = {e81, e81, e81, e81, e81, e81, e81, e81};
  const h16x8 ones = {(_Float16)1.f, (_Float16)1.f, (_Float16)1.f, (_Float16)1.f,
                      (_Float16)1.f, (_Float16)1.f, (_Float16)1.f, (_Float16)1.f};

  f32x4 acc[2][4] = {};
  f32x4 accd[2] = {};

  // ---- prologue: ballot chunk 0 into buf 0 ----
  {
    u32* wr = bits;
#pragma unroll 2
    for (int r = 0; r < 8; ++r) {
      int v0[4], v1[4];
#pragma unroll
      for (int k = 0; k < 4; ++k)
        v0[k] = __builtin_nontemporal_load(aP0 + (r * 4 + k) * 64);
#pragma unroll
      for (int k = 0; k < 4; ++k)
        v1[k] = __builtin_nontemporal_load(aP1 + (r * 4 + k) * 64);
#pragma unroll
      for (int k = 0; k < 4; ++k) {
        unsigned long long b = __ballot(v0[k] > 0);
        if (lane == 0) wr[r0 * 65 + r * 8 + 2 * k] = (u32)b;
        if (lane == 32) wr[r0 * 65 + r * 8 + 2 * k + 1] = (u32)(b >> 32);
      }
#pragma unroll
      for (int k = 0; k < 4; ++k) {
        unsigned long long b = __ballot(v1[k] > 0);
        if (lane == 0) wr[r1 * 65 + r * 8 + 2 * k] = (u32)b;
        if (lane == 32) wr[r1 * 65 + r * 8 + 2 * k + 1] = (u32)(b >> 32);
      }
    }
  }
  __syncthreads();

  // ---- pipelined main loop: consume chunk c, produce chunk c+1 ----
  for (int c = 0; c < 4; ++c) {
    const u32* rd0 = bits + (c & 1) * 2080 + col * 65 + q * 16;   // + it
    const u32* rd1 = rd0 + 16 * 65;
    u32* wr = bits + ((c & 1) ^ 1) * 2080;
    const int* p0 = aP0 + (c + 1) * 2048;
    const int* p1 = aP1 + (c + 1) * 2048;
    const bool prod = (c < 3);
#pragma unroll 2
    for (int it = 0; it < 16; ++it) {
      // produce: issue 4 A loads for chunk c+1 (row alternates per it)
      int a0 = 0, a1 = 0, a2 = 0, a3 = 0;
      const int gq = it >> 1;
      if (prod) {
        const int* pp = (it & 1) ? p1 : p0;
        a0 = __builtin_nontemporal_load(pp + (gq * 4 + 0) * 64);
        a1 = __builtin_nontemporal_load(pp + (gq * 4 + 1) * 64);
        a2 = __builtin_nontemporal_load(pp + (gq * 4 + 2) * 64);
        a3 = __builtin_nontemporal_load(pp + (gq * 4 + 3) * 64);
      }

      // consume iter (c, it)
      const u32 aw0 = rd0[it];
      const u32 aw1 = rd1[it];
      const int mcn = (it == 15) ? ((c + 1) * 64 + q * 16) : (mc + 1);
      uint4 nb0 = {}, nb1 = {}, nb2 = {}, nb3 = {};
      if (!(c == 3 && it == 15)) {
        nb0 = bp[(size_t)mcn * 256];
        nb1 = bp[(size_t)mcn * 256 + 64];
        nb2 = bp[(size_t)mcn * 256 + 128];
        nb3 = bp[(size_t)mcn * 256 + 192];
      }
      h16x8 edv = *(const h16x8*)(edp + (size_t)mc * 32);
      h16x8 e2v = *(const h16x8*)(e2p + (size_t)mc * 32);

      uint4 m0, m1;
      m0.x = hm2b(aw0, qs);     m0.y = hm2b(aw0, qs + 2);
      m0.z = hm2b(aw0, qs + 4); m0.w = hm2b(aw0, qs + 6);
      m1.x = hm2b(aw1, qs);     m1.y = hm2b(aw1, qs + 2);
      m1.z = hm2b(aw1, qs + 4); m1.w = hm2b(aw1, qs + 6);

      union { h16x8 v; uint4 u; } w0, w1, b0, b1, b2, b3;
      b0.u = bu0; b1.u = bu1; b2.u = bu2; b3.u = bu3;
      w0.v = __builtin_elementwise_max(edv * es80, e2v);
      w1.v = __builtin_elementwise_max(edv * es81, e2v);
      w0.u.x &= m0.x; w0.u.y &= m0.y; w0.u.z &= m0.z; w0.u.w &= m0.w;
      w1.u.x &= m1.x; w1.u.y &= m1.y; w1.u.z &= m1.z; w1.u.w &= m1.w;

      acc[0][0] = __builtin_amdgcn_mfma_f32_16x16x32_f16(w0.v, b0.v, acc[0][0], 0, 0, 0);
      acc[1][0] = __builtin_amdgcn_mfma_f32_16x16x32_f16(w1.v, b0.v, acc[1][0], 0, 0, 0);
      acc[0][1] = __builtin_amdgcn_mfma_f32_16x16x32_f16(w0.v, b1.v, acc[0][1], 0, 0, 0);
      acc[1][1] = __builtin_amdgcn_mfma_f32_16x16x32_f16(w1.v, b1.v, acc[1][1], 0, 0, 0);
      acc[0][2] = __builtin_amdgcn_mfma_f32_16x16x32_f16(w0.v, b2.v, acc[0][2], 0, 0, 0);
      acc[1][2] = __builtin_amdgcn_mfma_f32_16x16x32_f16(w1.v, b2.v, acc[1][2], 0, 0, 0);
      acc[0][3] = __builtin_amdgcn_mfma_f32_16x16x32_f16(w0.v, b3.v, acc[0][3], 0, 0, 0);
      acc[1][3] = __builtin_amdgcn_mfma_f32_16x16x32_f16(w1.v, b3.v, acc[1][3], 0, 0, 0);
      accd[0] = __builtin_amdgcn_mfma_f32_16x16x32_f16(w0.v, ones, accd[0], 0, 0, 0);
      accd[1] = __builtin_amdgcn_mfma_f32_16x16x32_f16(w1.v, ones, accd[1], 0, 0, 0);

      // produce: ballot + write bit-words for chunk c+1
      if (prod) {
        const int row = (it & 1) ? r1 : r0;
        unsigned long long b;
        b = __ballot(a0 > 0);
        if (lane == 0) wr[row * 65 + gq * 8 + 0] = (u32)b;
        if (lane == 32) wr[row * 65 + gq * 8 + 1] = (u32)(b >> 32);
        b = __ballot(a1 > 0);
        if (lane == 0) wr[row * 65 + gq * 8 + 2] = (u32)b;
        if (lane == 32) wr[row * 65 + gq * 8 + 3] = (u32)(b >> 32);
        b = __ballot(a2 > 0);
        if (lane == 0) wr[row * 65 + gq * 8 + 4] = (u32)b;
        if (lane == 32) wr[row * 65 + gq * 8 + 5] = (u32)(b >> 32);
        b = __ballot(a3 > 0);
        if (lane == 0) wr[row * 65 + gq * 8 + 6] = (u32)b;
        if (lane == 32) wr[row * 65 + gq * 8 + 7] = (u32)(b >> 32);
      }

      mc = mcn;
      bu0 = nb0; bu1 = nb1; bu2 = nb2; bu3 = nb3;
    }
    __syncthreads();
  }

  // ---- epilogue: bits dead; re-purpose LDS for reduction ----
  for (int i = t; i < 8320; i += 1024) Hsum[i] = 0.f;  // Hsum + Dsum
  __syncthreads();

  float* Hh = Hsum + h * 2048;
#pragma unroll
  for (int rt = 0; rt < 2; ++rt) {
#pragma unroll
    for (int dt = 0; dt < 4; ++dt)
#pragma unroll
      for (int r2 = 0; r2 < 4; ++r2)
        atomicAdd(&Hh[(rt * 16 + quad * 4 + r2) * 64 + dt * 16 + col],
                  acc[rt][dt][r2]);
    if (col == 0) {
#pragma unroll
      for (int r2 = 0; r2 < 4; ++r2)
        atomicAdd(&Dsum[h * 32 + rt * 16 + quad * 4 + r2], accd[rt][r2]);
    }
  }
  __syncthreads();

  for (int i = t; i < 2048; i += 1024) {
    int r = i >> 6;
    float v = 0.f;
#pragma unroll
    for (int hh = 0; hh < 4; ++hh) v += Hsum[hh * 2048 + i] / Dsum[hh * 32 + r];
    hp[i] = 0.25f * v;
  }
  __syncthreads();

#pragma unroll
  for (int i = 0; i < 2; ++i) {
    int r = wv * 2 + i;
    float v = hp[r * 64 + lane];
    float mx = v;
#pragma unroll
    for (int o = 32; o; o >>= 1) mx = fmaxf(mx, __shfl_xor(mx, o));
    float p = exp2f((v - mx) * L2E);
    float sm = p;
#pragma unroll
    for (int o = 32; o; o >>= 1) sm += __shfl_xor(sm, o);
    out[(size_t)(n0 + r) * HD + lane] = p / sm;
  }
}

extern "C" void kernel_launch(void* const* d_in, const int* in_sizes, int n_in,
                              void* d_out, int out_size, void* d_ws, size_t ws_size,
                              hipStream_t stream) {
  const float* F0 = (const float*)d_in[0];
  const float* E0 = (const float*)d_in[1];
  const int* A = (const int*)d_in[2];
  const float* Wf = (const float*)d_in[3];
  const float* We = (const float*)d_in[4];
  const float* a = (const float*)d_in[5];
  float* out = (float*)d_out;

  char* w = (char*)d_ws;
  float* esrc = (float*)w;        w += (size_t)NH * NN * 4;
  _Float16* edh = (_Float16*)w;   w += (size_t)NH * MM * 2;
  _Float16* ed2h = (_Float16*)w;  w += (size_t)NH * MM * 2;
  uint4* Bp = (uint4*)w;          w += (size_t)NH * HD * MM * 2;

  k_esrc<<<(NH * NN) / 256, 256, 0, stream>>>(F0, Wf, a, esrc);
  k_e1<<<(NH * MM / 8) / 4, 256, 0, stream>>>(E0, We, a, Bp, edh, ed2h);
  k_main<<<NN / NTILE, 1024, 0, stream>>>(A, Bp, esrc, edh, ed2h, out);
}

// Round 2
// 499.068 us; speedup vs baseline: 1.0164x; 1.0164x over previous
//
#include <hip/hip_runtime.h>
#include <hip/hip_fp16.h>

#define NN 8192
#define MM 8192
#define FD 128
#define EDm 128
#define HD 64
#define NH 4
#define NTILE 32

typedef float f32x4 __attribute__((ext_vector_type(4)));
typedef _Float16 h16x8 __attribute__((ext_vector_type(8)));
typedef unsigned int u32;
typedef unsigned long long u64;

// Fused: per-block recompute of vf[h][f] = Wf[h][f][:].a[h][:], then
// esrc[h][n] = F0[n,:] . vf[h,:]   (grid = 128 blocks -> full n coverage)
__global__ void k_esrc(const float* __restrict__ F0, const float* __restrict__ Wf,
                       const float* __restrict__ a, float* __restrict__ esrc) {
  __shared__ float vfL[NH * FD];
  int t = threadIdx.x;  // 256
#pragma unroll
  for (int r = 0; r < 2; ++r) {
    int idx = t + r * 256;            // 512 entries
    int h = idx >> 7, f = idx & 127;
    const float* w = Wf + (size_t)(h * FD + f) * HD;
    const float* av = a + h * HD;
    float s = 0.f;
#pragma unroll
    for (int d = 0; d < HD; ++d) s += w[d] * av[d];
    vfL[idx] = s;
  }
  __syncthreads();
  int g = blockIdx.x * 256 + t;       // 0..32767
  int n = g >> 2, h = g & 3;
  const float4* fr = (const float4*)(F0 + (size_t)n * FD);
  const float4* vr = (const float4*)(vfL + h * FD);
  float s = 0.f;
#pragma unroll
  for (int i = 0; i < FD / 4; ++i) {
    float4 x = fr[i], y = vr[i];
    s += x.x * y.x + x.y * y.y + x.z * y.z + x.w * y.w;
  }
  esrc[h * NN + n] = s;
}

// E1 = E0·We per head; writes Bp directly in MFMA-B fragment order
// (wave = 8 m-rows, lane = d), plus ed/ed2 fp16 exp tables. No E1T pass.
__global__ void k_e1(const float* __restrict__ E0, const float* __restrict__ We,
                     const float* __restrict__ a, uint4* __restrict__ Bp,
                     _Float16* __restrict__ edh, _Float16* __restrict__ ed2h) {
  int wid = (blockIdx.x * blockDim.x + threadIdx.x) >> 6;  // 4096 waves
  int lane = threadIdx.x & 63;
  int h = wid >> 10;
  int mg = wid & 1023;
  int m = mg * 8;
  const float* we = We + (size_t)h * EDm * HD + lane;
  const float* e0r = E0 + (size_t)m * EDm;
  float ac[8] = {};
#pragma unroll 4
  for (int e = 0; e < EDm; ++e) {
    float wv = we[e * HD];
#pragma unroll
    for (int j = 0; j < 8; ++j) ac[j] += e0r[j * EDm + e] * wv;
  }
  // Bp[h][mc][dt][quad*16+col]: 8 fp16 (m..m+7) at d = dt*16+col
  int mc = mg >> 2, quad = mg & 3, dt = lane >> 4, col = lane & 15;
  union { h16x8 v; uint4 u; } hv;
#pragma unroll
  for (int j = 0; j < 8; ++j) hv.v[j] = (_Float16)ac[j];
  Bp[(((size_t)h * 256 + mc) * 4 + dt) * 64 + quad * 16 + col] = hv.u;

  float av = a[h * HD + lane];
  float d[8];
#pragma unroll
  for (int j = 0; j < 8; ++j) d[j] = ac[j] * av;
#pragma unroll
  for (int o = 32; o; o >>= 1)
#pragma unroll
    for (int j = 0; j < 8; ++j) d[j] += __shfl_xor(d[j], o);
  if (lane == 0) {
    const float L2E = 1.4426950408889634f;
    union { h16x8 v; uint4 u; } e1, e2;
#pragma unroll
    for (int j = 0; j < 8; ++j) {
      e1.v[j] = (_Float16)exp2f(d[j] * L2E);
      e2.v[j] = (_Float16)exp2f(0.2f * d[j] * L2E);
    }
    *(uint4*)(edh + (size_t)h * MM + m) = e1.u;
    *(uint4*)(ed2h + (size_t)h * MM + m) = e2.u;
  }
}

// Pack A>0 into bit words: bitsG[n][256] u32 (bit for column m at word m>>5,
// bit m&31). Pure BW kernel: 256 MB read / 8 MB write, 1 wave per row.
__global__ void k_pack(const int* __restrict__ A, u32* __restrict__ bitsG) {
  const int wid = (blockIdx.x * blockDim.x + threadIdx.x) >> 6;  // row
  const int lane = threadIdx.x & 63;
  const int* ap = A + (size_t)wid * MM + lane;
  u32* op = bitsG + (size_t)wid * 256;
#pragma unroll 2
  for (int c = 0; c < 128; c += 8) {
    int v[8];
#pragma unroll
    for (int k = 0; k < 8; ++k)
      v[k] = __builtin_nontemporal_load(ap + (c + k) * 64);
    u64 b[8];
#pragma unroll
    for (int k = 0; k < 8; ++k) b[k] = __ballot(v[k] > 0);
    if (lane == 0) {
#pragma unroll
      for (int k = 0; k < 8; k += 2) {
        uint4 w = {(u32)b[k], (u32)(b[k] >> 32), (u32)b[k + 1], (u32)(b[k + 1] >> 32)};
        *(uint4*)(op + 2 * (c + k)) = w;
      }
    }
  }
}

// bit b0 at `bit`, b1 at bit+1 -> (b0?0xffff:0)|(b1?0xffff0000:0)
__device__ __forceinline__ u32 hm2b(u32 w, int bit) {
  return (((w >> bit) & 1u) | (((w >> (bit + 1)) & 1u) << 16)) * 0xffffu;
}

// Main: 256 blocks x 1024 thr (1 block/CU, occupancy is grid-limited so VGPRs
// are free). Prologue: 32 KB packed bits global->LDS (stride 260 words: 16B
// aligned rows, 2-way-free bank pattern). Then 64 flat iterations, zero
// barriers, no ballots; Bp/ed/e2/bits all on a 2-iteration register pipeline
// (static [it&1] slots under unroll 2). Epilogue unchanged.
__global__ __launch_bounds__(1024, 4) void k_main(
    const u32* __restrict__ bitsG, const uint4* __restrict__ Bp,
    const float* __restrict__ esrc, const _Float16* __restrict__ edh,
    const _Float16* __restrict__ ed2h, float* __restrict__ out) {
  __shared__ __align__(16) char smem[41472];
  u32* bits = (u32*)smem;              // [32 rows][260 words] = 33280 B
  float* Hsum = (float*)smem;          // epilogue alias: [4][32][64] 32 KB
  float* Dsum = (float*)(smem + 32768);// [4][32]
  float* hp = (float*)(smem + 33280);  // [32][64]

  const int t = threadIdx.x;
  const int lane = t & 63;
  const int wv = t >> 6;       // 0..15
  const int h = wv & 3;        // head
  const int q = wv >> 2;       // m-quarter (2048 m per wave)
  const int col = lane & 15;
  const int quad = lane >> 4;
  const int qs = quad * 8;
  const int n0 = blockIdx.x * NTILE;
  const float L2E = 1.4426950408889634f;

  // ---- prologue: bits tile (32 rows x 256 words) -> LDS ----
#pragma unroll
  for (int i = 0; i < 2; ++i) {
    int tid = t + i * 1024;            // 0..2047
    int row = tid >> 6, w4 = tid & 63; // uint4 index in row
    uint4 v = *(const uint4*)(bitsG + (size_t)(n0 + row) * 256 + w4 * 4);
    *(uint4*)(bits + row * 260 + w4 * 4) = v;
  }

  float s0 = esrc[h * NN + n0 + col];
  float s1 = esrc[h * NN + n0 + 16 + col];
  _Float16 e80 = (_Float16)exp2f(0.8f * s0 * L2E);
  _Float16 e81 = (_Float16)exp2f(0.8f * s1 * L2E);
  h16x8 es80 = {e80, e80, e80, e80, e80, e80, e80, e80};
  h16x8 es81 = {e81, e81, e81, e81, e81, e81, e81, e81};
  const h16x8 ones = {(_Float16)1.f, (_Float16)1.f, (_Float16)1.f, (_Float16)1.f,
                      (_Float16)1.f, (_Float16)1.f, (_Float16)1.f, (_Float16)1.f};

  const _Float16* edp = edh + (size_t)h * MM + qs;    // + w*32
  const _Float16* e2p = ed2h + (size_t)h * MM + qs;   // + w*32
  const uint4* bp = Bp + (size_t)h * 65536 + lane;    // + w*256 + dt*64

  // 2-deep register pipeline state (slot = it&1)
  uint4 b0s[2], b1s[2], b2s[2], b3s[2];
  h16x8 eds[2], e2s[2];
  u32 aw0s[2], aw1s[2];
#pragma unroll
  for (int i = 0; i < 2; ++i) {
    size_t w = (size_t)(q * 64 + i);
    b0s[i] = bp[w * 256];
    b1s[i] = bp[w * 256 + 64];
    b2s[i] = bp[w * 256 + 128];
    b3s[i] = bp[w * 256 + 192];
    eds[i] = *(const h16x8*)(edp + w * 32);
    e2s[i] = *(const h16x8*)(e2p + w * 32);
  }
  __syncthreads();

  const u32* rd0 = bits + col * 260 + q * 64;         // + it
  const u32* rd1 = bits + (col + 16) * 260 + q * 64;  // + it
  aw0s[0] = rd0[0]; aw1s[0] = rd1[0];
  aw0s[1] = rd0[1]; aw1s[1] = rd1[1];

  f32x4 acc[2][4] = {};
  f32x4 accd[2] = {};

#pragma unroll 2
  for (int it = 0; it < 64; ++it) {
    const int s = it & 1;
    // consume-state locals
    const u32 aw0 = aw0s[s], aw1 = aw1s[s];
    union { h16x8 v; uint4 u; } w0, w1, b0, b1, b2, b3;
    b0.u = b0s[s]; b1.u = b1s[s]; b2.u = b2s[s]; b3.u = b3s[s];
    const h16x8 edv = eds[s], e2v = e2s[s];

    // prefetch it+2 into slot s (clamped redundant reload on the tail)
    int ip = it + 2; if (ip > 63) ip = 63;
    const size_t wn = (size_t)(q * 64 + ip);
    b0s[s] = bp[wn * 256];
    b1s[s] = bp[wn * 256 + 64];
    b2s[s] = bp[wn * 256 + 128];
    b3s[s] = bp[wn * 256 + 192];
    eds[s] = *(const h16x8*)(edp + wn * 32);
    e2s[s] = *(const h16x8*)(e2p + wn * 32);
    aw0s[s] = rd0[ip];
    aw1s[s] = rd1[ip];

    uint4 m0, m1;
    m0.x = hm2b(aw0, qs);     m0.y = hm2b(aw0, qs + 2);
    m0.z = hm2b(aw0, qs + 4); m0.w = hm2b(aw0, qs + 6);
    m1.x = hm2b(aw1, qs);     m1.y = hm2b(aw1, qs + 2);
    m1.z = hm2b(aw1, qs + 4); m1.w = hm2b(aw1, qs + 6);

    w0.v = __builtin_elementwise_max(edv * es80, e2v);
    w1.v = __builtin_elementwise_max(edv * es81, e2v);
    w0.u.x &= m0.x; w0.u.y &= m0.y; w0.u.z &= m0.z; w0.u.w &= m0.w;
    w1.u.x &= m1.x; w1.u.y &= m1.y; w1.u.z &= m1.z; w1.u.w &= m1.w;

    acc[0][0] = __builtin_amdgcn_mfma_f32_16x16x32_f16(w0.v, b0.v, acc[0][0], 0, 0, 0);
    acc[1][0] = __builtin_amdgcn_mfma_f32_16x16x32_f16(w1.v, b0.v, acc[1][0], 0, 0, 0);
    acc[0][1] = __builtin_amdgcn_mfma_f32_16x16x32_f16(w0.v, b1.v, acc[0][1], 0, 0, 0);
    acc[1][1] = __builtin_amdgcn_mfma_f32_16x16x32_f16(w1.v, b1.v, acc[1][1], 0, 0, 0);
    acc[0][2] = __builtin_amdgcn_mfma_f32_16x16x32_f16(w0.v, b2.v, acc[0][2], 0, 0, 0);
    acc[1][2] = __builtin_amdgcn_mfma_f32_16x16x32_f16(w1.v, b2.v, acc[1][2], 0, 0, 0);
    acc[0][3] = __builtin_amdgcn_mfma_f32_16x16x32_f16(w0.v, b3.v, acc[0][3], 0, 0, 0);
    acc[1][3] = __builtin_amdgcn_mfma_f32_16x16x32_f16(w1.v, b3.v, acc[1][3], 0, 0, 0);
    accd[0] = __builtin_amdgcn_mfma_f32_16x16x32_f16(w0.v, ones, accd[0], 0, 0, 0);
    accd[1] = __builtin_amdgcn_mfma_f32_16x16x32_f16(w1.v, ones, accd[1], 0, 0, 0);
  }
  __syncthreads();   // bits dead; re-purpose LDS for reduction

  for (int i = t; i < 8320; i += 1024) Hsum[i] = 0.f;  // Hsum + Dsum
  __syncthreads();

  float* Hh = Hsum + h * 2048;
#pragma unroll
  for (int rt = 0; rt < 2; ++rt) {
#pragma unroll
    for (int dt = 0; dt < 4; ++dt)
#pragma unroll
      for (int r2 = 0; r2 < 4; ++r2)
        atomicAdd(&Hh[(rt * 16 + quad * 4 + r2) * 64 + dt * 16 + col],
                  acc[rt][dt][r2]);
    if (col == 0) {
#pragma unroll
      for (int r2 = 0; r2 < 4; ++r2)
        atomicAdd(&Dsum[h * 32 + rt * 16 + quad * 4 + r2], accd[rt][r2]);
    }
  }
  __syncthreads();

  for (int i = t; i < 2048; i += 1024) {
    int r = i >> 6;
    float v = 0.f;
#pragma unroll
    for (int hh = 0; hh < 4; ++hh) v += Hsum[hh * 2048 + i] / Dsum[hh * 32 + r];
    hp[i] = 0.25f * v;
  }
  __syncthreads();

#pragma unroll
  for (int i = 0; i < 2; ++i) {
    int r = wv * 2 + i;
    float v = hp[r * 64 + lane];
    float mx = v;
#pragma unroll
    for (int o = 32; o; o >>= 1) mx = fmaxf(mx, __shfl_xor(mx, o));
    float p = exp2f((v - mx) * L2E);
    float sm = p;
#pragma unroll
    for (int o = 32; o; o >>= 1) sm += __shfl_xor(sm, o);
    out[(size_t)(n0 + r) * HD + lane] = p / sm;
  }
}

extern "C" void kernel_launch(void* const* d_in, const int* in_sizes, int n_in,
                              void* d_out, int out_size, void* d_ws, size_t ws_size,
                              hipStream_t stream) {
  const float* F0 = (const float*)d_in[0];
  const float* E0 = (const float*)d_in[1];
  const int* A = (const int*)d_in[2];
  const float* Wf = (const float*)d_in[3];
  const float* We = (const float*)d_in[4];
  const float* a = (const float*)d_in[5];
  float* out = (float*)d_out;

  char* w = (char*)d_ws;
  float* esrc = (float*)w;        w += (size_t)NH * NN * 4;
  _Float16* edh = (_Float16*)w;   w += (size_t)NH * MM * 2;
  _Float16* ed2h = (_Float16*)w;  w += (size_t)NH * MM * 2;
  uint4* Bp = (uint4*)w;          w += (size_t)NH * HD * MM * 2;
  u32* bitsG = (u32*)w;           w += (size_t)NN * 256 * 4;

  k_pack<<<NN * 64 / 256, 256, 0, stream>>>(A, bitsG);
  k_esrc<<<(NH * NN) / 256, 256, 0, stream>>>(F0, Wf, a, esrc);
  k_e1<<<(NH * MM / 8) / 4, 256, 0, stream>>>(E0, We, a, Bp, edh, ed2h);
  k_main<<<NN / NTILE, 1024, 0, stream>>>(bitsG, Bp, esrc, edh, ed2h, out);
}

// Round 3
// 453.096 us; speedup vs baseline: 1.1195x; 1.1015x over previous
//
#include <hip/hip_runtime.h>
#include <hip/hip_fp16.h>

#define NN 8192
#define MM 8192
#define FD 128
#define EDm 128
#define HD 64
#define NH 4

typedef float f32x4 __attribute__((ext_vector_type(4)));
typedef _Float16 h16x8 __attribute__((ext_vector_type(8)));
typedef unsigned int u32;
typedef unsigned long long u64;

// ---------------- fused prep: pack(A) + esrc + e1 in one grid ----------------
// blocks [0,2048): pack A bits (4 waves/block, 1 row/wave)
// blocks [2048,2176): esrc (128 blocks)
// blocks [2176,3200): e1 (1024 blocks)
__global__ void k_prep(const int* __restrict__ A, u32* __restrict__ bitsG,
                       const float* __restrict__ F0, const float* __restrict__ Wf,
                       const float* __restrict__ aa, float* __restrict__ esrc,
                       const float* __restrict__ E0, const float* __restrict__ We,
                       uint4* __restrict__ Bp, _Float16* __restrict__ edh,
                       _Float16* __restrict__ ed2h) {
  __shared__ float vfL[NH * FD];
  const int bid = blockIdx.x;
  const int t = threadIdx.x;          // 256
  const int lane = t & 63;

  if (bid < 2048) {
    // ---- pack: bitsG[n][256] u32, bit for col m at word m>>5, bit m&31 ----
    const int row = bid * 4 + (t >> 6);
    const int* ap = A + (size_t)row * MM + lane;
    u32* op = bitsG + (size_t)row * 256;
#pragma unroll 2
    for (int c = 0; c < 128; c += 8) {
      int v[8];
#pragma unroll
      for (int k = 0; k < 8; ++k)
        v[k] = __builtin_nontemporal_load(ap + (c + k) * 64);
      u64 b[8];
#pragma unroll
      for (int k = 0; k < 8; ++k) b[k] = __ballot(v[k] > 0);
      if (lane == 0) {
#pragma unroll
        for (int k = 0; k < 8; k += 2) {
          uint4 w = {(u32)b[k], (u32)(b[k] >> 32), (u32)b[k + 1], (u32)(b[k + 1] >> 32)};
          *(uint4*)(op + 2 * (c + k)) = w;
        }
      }
    }
  } else if (bid < 2176) {
    // ---- esrc: vf[h][f] = Wf[h][f][:].a[h][:]; esrc[h][n] = F0[n,:].vf[h,:] ----
    const int b2 = bid - 2048;
#pragma unroll
    for (int r = 0; r < 2; ++r) {
      int idx = t + r * 256;
      int h = idx >> 7, f = idx & 127;
      const float* w = Wf + (size_t)(h * FD + f) * HD;
      const float* av = aa + h * HD;
      float s = 0.f;
#pragma unroll
      for (int d = 0; d < HD; ++d) s += w[d] * av[d];
      vfL[idx] = s;
    }
    __syncthreads();
    int g = b2 * 256 + t;             // 0..32767
    int n = g >> 2, h = g & 3;
    const float4* fr = (const float4*)(F0 + (size_t)n * FD);
    const float4* vr = (const float4*)(vfL + h * FD);
    float s = 0.f;
#pragma unroll
    for (int i = 0; i < FD / 4; ++i) {
      float4 x = fr[i], y = vr[i];
      s += x.x * y.x + x.y * y.y + x.z * y.z + x.w * y.w;
    }
    esrc[h * NN + n] = s;
  } else {
    // ---- e1: E1 = E0·We; Bp in MFMA-B fragment order + ed/ed2 fp16 tables ----
    const int wid = (bid - 2176) * 4 + (t >> 6);   // 0..4095
    const int h = wid >> 10;
    const int mg = wid & 1023;
    const int m = mg * 8;
    const float* we = We + (size_t)h * EDm * HD + lane;
    const float* e0r = E0 + (size_t)m * EDm;
    float ac[8] = {};
#pragma unroll 4
    for (int e = 0; e < EDm; ++e) {
      float wv = we[e * HD];
#pragma unroll
      for (int j = 0; j < 8; ++j) ac[j] += e0r[j * EDm + e] * wv;
    }
    int mc = mg >> 2, quad = mg & 3, dt = lane >> 4, col = lane & 15;
    union { h16x8 v; uint4 u; } hv;
#pragma unroll
    for (int j = 0; j < 8; ++j) hv.v[j] = (_Float16)ac[j];
    Bp[(((size_t)h * 256 + mc) * 4 + dt) * 64 + quad * 16 + col] = hv.u;

    float av = aa[h * HD + lane];
    float d[8];
#pragma unroll
    for (int j = 0; j < 8; ++j) d[j] = ac[j] * av;
#pragma unroll
    for (int o = 32; o; o >>= 1)
#pragma unroll
      for (int j = 0; j < 8; ++j) d[j] += __shfl_xor(d[j], o);
    if (lane == 0) {
      const float L2E = 1.4426950408889634f;
      union { h16x8 v; uint4 u; } e1, e2;
#pragma unroll
      for (int j = 0; j < 8; ++j) {
        e1.v[j] = (_Float16)exp2f(d[j] * L2E);
        e2.v[j] = (_Float16)exp2f(0.2f * d[j] * L2E);
      }
      *(uint4*)(edh + (size_t)h * MM + m) = e1.u;
      *(uint4*)(ed2h + (size_t)h * MM + m) = e2.u;
    }
  }
}

// bit b0 at `bit`, b1 at bit+1 -> (b0?0xffff:0)|(b1?0xffff0000:0)
__device__ __forceinline__ u32 hm2b(u32 w, int bit) {
  return (((w >> bit) & 1u) | (((w >> (bit + 1)) & 1u) << 16)) * 0xffffu;
}

// Main: grid = 64 n-tiles x 4 m-quarters (bid = ntile*4 + mq; mq = bid&3 so
// each XCD keeps ONE 1MB Bp slice L2-resident under round-robin dispatch).
// Block: 1024 thr, 16 waves = 4 heads x 4 rowgroups(32 n-rows). 64 iters over
// the 2048-m quarter, depth-1 register pipeline, zero in-loop barriers.
// Writes f32 partials (Npart/Dpart) directly - no reduction epilogue.
__global__ __launch_bounds__(1024, 4) void k_main(
    const u32* __restrict__ bitsG, const uint4* __restrict__ Bp,
    const float* __restrict__ esrc, const _Float16* __restrict__ edh,
    const _Float16* __restrict__ ed2h, float* __restrict__ Npart,
    float* __restrict__ Dpart) {
  __shared__ __align__(16) u32 bits[128 * 68];   // [128 rows][64 words +4 pad]

  const int t = threadIdx.x;
  const int lane = t & 63;
  const int wv = t >> 6;       // 0..15
  const int h = wv & 3;        // head
  const int g = wv >> 2;       // rowgroup (32 rows)
  const int col = lane & 15;
  const int quad = lane >> 4;
  const int qs = quad * 8;
  const int mq = blockIdx.x & 3;
  const int n0 = (blockIdx.x >> 2) * 128;
  const float L2E = 1.4426950408889634f;

  // ---- prologue: bits tile (128 rows x 64 words of this m-quarter) -> LDS ----
#pragma unroll
  for (int i = 0; i < 2; ++i) {
    int idx = t + i * 1024;            // 0..2047
    int row = idx >> 4, u4 = idx & 15;
    uint4 v = *(const uint4*)(bitsG + (size_t)(n0 + row) * 256 + mq * 64 + u4 * 4);
    *(uint4*)(bits + row * 68 + u4 * 4) = v;
  }

  const uint4* bp = Bp + (size_t)h * 65536 + (size_t)mq * 64 * 256 + lane;
  const _Float16* edp = edh + (size_t)h * MM + mq * 2048 + qs;
  const _Float16* e2p = ed2h + (size_t)h * MM + mq * 2048 + qs;

  // preload iter 0 (global; overlaps the barrier)
  uint4 bu0 = bp[0], bu1 = bp[64], bu2 = bp[128], bu3 = bp[192];
  h16x8 edv = *(const h16x8*)edp;
  h16x8 e2v = *(const h16x8*)e2p;

  float s0 = esrc[h * NN + n0 + g * 32 + col];
  float s1 = esrc[h * NN + n0 + g * 32 + 16 + col];
  _Float16 e80 = (_Float16)exp2f(0.8f * s0 * L2E);
  _Float16 e81 = (_Float16)exp2f(0.8f * s1 * L2E);
  h16x8 es80 = {e80, e80, e80, e80, e80, e80, e80, e80};
  h16x8 es81 = {e81, e81, e81, e81, e81, e81, e81, e81};
  const h16x8 ones = {(_Float16)1.f, (_Float16)1.f, (_Float16)1.f, (_Float16)1.f,
                      (_Float16)1.f, (_Float16)1.f, (_Float16)1.f, (_Float16)1.f};

  __syncthreads();

  const u32* rd0 = bits + (g * 32 + col) * 68;        // + it
  const u32* rd1 = bits + (g * 32 + 16 + col) * 68;   // + it
  u32 aw0 = rd0[0], aw1 = rd1[0];

  f32x4 acc[2][4] = {};
  f32x4 accd[2] = {};

  for (int it = 0; it < 64; ++it) {
    // depth-1 prefetch (clamped redundant reload on the tail)
    const int ip = (it < 63) ? it + 1 : 63;
    const u32 naw0 = rd0[ip];
    const u32 naw1 = rd1[ip];
    const uint4 nb0 = bp[ip * 256];
    const uint4 nb1 = bp[ip * 256 + 64];
    const uint4 nb2 = bp[ip * 256 + 128];
    const uint4 nb3 = bp[ip * 256 + 192];
    const h16x8 nedv = *(const h16x8*)(edp + ip * 32);
    const h16x8 ne2v = *(const h16x8*)(e2p + ip * 32);

    uint4 m0, m1;
    m0.x = hm2b(aw0, qs);     m0.y = hm2b(aw0, qs + 2);
    m0.z = hm2b(aw0, qs + 4); m0.w = hm2b(aw0, qs + 6);
    m1.x = hm2b(aw1, qs);     m1.y = hm2b(aw1, qs + 2);
    m1.z = hm2b(aw1, qs + 4); m1.w = hm2b(aw1, qs + 6);

    union { h16x8 v; uint4 u; } w0, w1, b0, b1, b2, b3;
    b0.u = bu0; b1.u = bu1; b2.u = bu2; b3.u = bu3;
    w0.v = __builtin_elementwise_max(edv * es80, e2v);
    w1.v = __builtin_elementwise_max(edv * es81, e2v);
    w0.u.x &= m0.x; w0.u.y &= m0.y; w0.u.z &= m0.z; w0.u.w &= m0.w;
    w1.u.x &= m1.x; w1.u.y &= m1.y; w1.u.z &= m1.z; w1.u.w &= m1.w;

    acc[0][0] = __builtin_amdgcn_mfma_f32_16x16x32_f16(w0.v, b0.v, acc[0][0], 0, 0, 0);
    acc[1][0] = __builtin_amdgcn_mfma_f32_16x16x32_f16(w1.v, b0.v, acc[1][0], 0, 0, 0);
    acc[0][1] = __builtin_amdgcn_mfma_f32_16x16x32_f16(w0.v, b1.v, acc[0][1], 0, 0, 0);
    acc[1][1] = __builtin_amdgcn_mfma_f32_16x16x32_f16(w1.v, b1.v, acc[1][1], 0, 0, 0);
    acc[0][2] = __builtin_amdgcn_mfma_f32_16x16x32_f16(w0.v, b2.v, acc[0][2], 0, 0, 0);
    acc[1][2] = __builtin_amdgcn_mfma_f32_16x16x32_f16(w1.v, b2.v, acc[1][2], 0, 0, 0);
    acc[0][3] = __builtin_amdgcn_mfma_f32_16x16x32_f16(w0.v, b3.v, acc[0][3], 0, 0, 0);
    acc[1][3] = __builtin_amdgcn_mfma_f32_16x16x32_f16(w1.v, b3.v, acc[1][3], 0, 0, 0);
    accd[0] = __builtin_amdgcn_mfma_f32_16x16x32_f16(w0.v, ones, accd[0], 0, 0, 0);
    accd[1] = __builtin_amdgcn_mfma_f32_16x16x32_f16(w1.v, ones, accd[1], 0, 0, 0);

    aw0 = naw0; aw1 = naw1; edv = nedv; e2v = ne2v;
    bu0 = nb0; bu1 = nb1; bu2 = nb2; bu3 = nb3;
  }

  // ---- write per-(mq,h) partials; C row = rt*16 + quad*4 + r2, d = dt*16+col
  float* np = Npart + (((size_t)(mq * 4 + h) * NN) + n0 + g * 32) * HD;
#pragma unroll
  for (int rt = 0; rt < 2; ++rt)
#pragma unroll
    for (int dt = 0; dt < 4; ++dt)
#pragma unroll
      for (int r2 = 0; r2 < 4; ++r2)
        np[(size_t)(rt * 16 + quad * 4 + r2) * HD + dt * 16 + col] = acc[rt][dt][r2];
  if (col == 0) {
    float* dp = Dpart + (size_t)(mq * 4 + h) * NN + n0 + g * 32;
#pragma unroll
    for (int rt = 0; rt < 2; ++rt)
#pragma unroll
      for (int r2 = 0; r2 < 4; ++r2)
        dp[rt * 16 + quad * 4 + r2] = accd[rt][r2];
  }
}

// Combine: sum 4 mq-partials, head-mean, row softmax. 1 wave per n-row.
__global__ void k_comb(const float* __restrict__ Npart,
                       const float* __restrict__ Dpart,
                       float* __restrict__ out) {
  const int t = threadIdx.x;           // 256
  const int lane = t & 63;
  const int n = blockIdx.x * 4 + (t >> 6);
  const float L2E = 1.4426950408889634f;

  float v = 0.f;
#pragma unroll
  for (int h = 0; h < NH; ++h) {
    float num = 0.f, den = 0.f;
#pragma unroll
    for (int mq = 0; mq < 4; ++mq) {
      num += Npart[(((size_t)(mq * 4 + h) * NN) + n) * HD + lane];
      den += Dpart[(size_t)(mq * 4 + h) * NN + n];
    }
    v += num / den;
  }
  v *= 0.25f;

  float mx = v;
#pragma unroll
  for (int o = 32; o; o >>= 1) mx = fmaxf(mx, __shfl_xor(mx, o));
  float p = exp2f((v - mx) * L2E);
  float sm = p;
#pragma unroll
  for (int o = 32; o; o >>= 1) sm += __shfl_xor(sm, o);
  out[(size_t)n * HD + lane] = p / sm;
}

extern "C" void kernel_launch(void* const* d_in, const int* in_sizes, int n_in,
                              void* d_out, int out_size, void* d_ws, size_t ws_size,
                              hipStream_t stream) {
  const float* F0 = (const float*)d_in[0];
  const float* E0 = (const float*)d_in[1];
  const int* A = (const int*)d_in[2];
  const float* Wf = (const float*)d_in[3];
  const float* We = (const float*)d_in[4];
  const float* a = (const float*)d_in[5];
  float* out = (float*)d_out;

  char* w = (char*)d_ws;
  float* esrc = (float*)w;        w += (size_t)NH * NN * 4;
  _Float16* edh = (_Float16*)w;   w += (size_t)NH * MM * 2;
  _Float16* ed2h = (_Float16*)w;  w += (size_t)NH * MM * 2;
  uint4* Bp = (uint4*)w;          w += (size_t)NH * HD * MM * 2;
  u32* bitsG = (u32*)w;           w += (size_t)NN * 256 * 4;
  float* Npart = (float*)w;       w += (size_t)16 * NN * HD * 4;
  float* Dpart = (float*)w;       w += (size_t)16 * NN * 4;

  k_prep<<<3200, 256, 0, stream>>>(A, bitsG, F0, Wf, a, esrc, E0, We, Bp, edh, ed2h);
  k_main<<<256, 1024, 0, stream>>>(bitsG, Bp, esrc, edh, ed2h, Npart, Dpart);
  k_comb<<<NN / 4, 256, 0, stream>>>(Npart, Dpart, out);
}